// Round 3
// baseline (207.816 us; speedup 1.0000x reference)
//
#include <hip/hip_runtime.h>
#include <hip/hip_bf16.h>
#include <math.h>

// Topic-verb attention over ragged spans — algebraic collapse:
//   scores[n,l] = value[n,l] . w + c,  w = (k_w^T @ query)/16, c = (k_b.query)/16
//   query = q_w @ topic_emb + q_b
// Per span: gather <=8 rows of V, dot each with w, softmax, weighted sum.
// Memory-bound on the V gather (~65 MB unique-row HBM fetch per iteration).
//
// R2: nontemporal float4 out stores; verb_ids as 2x int4.   [195.3 us]
// R3: fused prep + 32-bit saddr gather                       [206.9 us REGRESSED]
// R4: decomposition — tva_main reverted byte-for-byte to R2's proven version
//     (64-bit addressing); fused prep kept. Isolates which R3 change regressed.
//     (R4 bench was an infra failure — this is the same kernel resubmitted.)
// Measured floor context: harness reset (480 MB ws fill + input restore)
// accounts for ~165 us of dur_us; controllable kernel share ~30 us.

#define SPAN_L 8
#define DW 300
#define DT 256
#define PREP_WBLOCKS 19   // 19 blocks x 16 d-columns = 304 >= 300

typedef float f32x4 __attribute__((ext_vector_type(4)));

__device__ __forceinline__ float wave_reduce(float p) {
    #pragma unroll
    for (int m = 1; m < 64; m <<= 1) p += __shfl_xor(p, m, 64);
    return p;
}

// ---------- fused prep: query (LDS-local) -> w[300], c ----------
// Every block recomputes query[256] = q_w @ topic_emb + q_b into LDS
// (redundant across 20 blocks; q_w reads merge in L2/L3 — it was just
// restored, so it's cache-hot). Then:
//   blocks 0..18: w[d] = (sum_t k_w[t,d]*query[t])/16 for 16 d's each
//   block 19:     c    = (k_b . query)/16
__global__ __launch_bounds__(1024) void tva_prep(
    const float* __restrict__ topic_emb,
    const float* __restrict__ q_w,
    const float* __restrict__ q_b,
    const float* __restrict__ k_w,
    const float* __restrict__ k_b,
    float* __restrict__ wc)
{
    __shared__ float q_lds[DT];
    __shared__ float part[64][16];
    const int tid  = threadIdx.x;
    const int wave = tid >> 6;          // 0..15
    const int lane = tid & 63;

    // phase 1: query rows, 16 per wave, 64-lane dot + butterfly reduce
    const float4 te4 = ((const float4*)topic_emb)[lane];   // 256 f32 = 64 float4
    #pragma unroll 4
    for (int i = 0; i < 16; ++i) {
        const int r = wave * 16 + i;                       // 0..255
        const float4 qr = ((const float4*)(q_w + r * DT))[lane];
        float p = qr.x * te4.x + qr.y * te4.y + qr.z * te4.z + qr.w * te4.w;
        p = wave_reduce(p);
        if (lane == 0) q_lds[r] = p + q_b[r];
    }
    __syncthreads();

    const int b = blockIdx.x;
    if (b == PREP_WBLOCKS) {            // c block
        if (wave == 0) {
            float p = 0.f;
            #pragma unroll
            for (int j = 0; j < 4; ++j) {
                const int t = lane + 64 * j;
                p += k_b[t] * q_lds[t];
            }
            p = wave_reduce(p);
            if (lane == 0) wc[DW] = p * 0.0625f;
        }
        return;
    }

    // phase 2: w columns. thread = (t0 0..63, dj 0..15); 64B coalesced
    // k_w segments per 16-lane group; LDS tree for the 64 t0-partials.
    const int t0 = tid >> 4;
    const int dj = tid & 15;
    const int d  = b * 16 + dj;         // 0..303
    float p = 0.f;
    if (d < DW) {
        #pragma unroll
        for (int k = 0; k < 4; ++k) {
            const int t = t0 + 64 * k;
            p += k_w[t * DW + d] * q_lds[t];
        }
    }
    part[t0][dj] = p;
    __syncthreads();
    if (tid < 16) {
        const int dd = b * 16 + tid;
        if (dd < DW) {
            float s = 0.f;
            #pragma unroll
            for (int k = 0; k < 64; ++k) s += part[k][tid];
            wc[dd] = s * 0.0625f;
        }
    }
}

// ---------- main: one wave per span (byte-identical to the proven R2 version) ----
__global__ __launch_bounds__(256, 4) void tva_main(
    const float* __restrict__ V,          // [100000, 300]
    const int*   __restrict__ verb_ids,   // [N, 8]
    const int*   __restrict__ span_len,   // [N]
    const float* __restrict__ wc,         // [301]: w[300], c
    float* __restrict__ out,              // [N, 300]
    int N)
{
    const int wave = threadIdx.x >> 6;
    const int lane = threadIdx.x & 63;
    const int n = blockIdx.x * 4 + wave;
    if (n >= N) return;

    const bool tail = (lane < 11);        // 300 floats = 75 float4 = 64 + 11
    const float4* w4 = (const float4*)wc;
    const float4 wv0 = w4[lane];
    const float4 wv1 = tail ? w4[64 + lane] : make_float4(0.f, 0.f, 0.f, 0.f);
    const float  c   = wc[DW];

    const int len = span_len[n];          // wave-uniform

    // ids as two int4 (wave-uniform addresses -> 2 dwordx4 instead of 8 dword)
    const int4* ids4 = (const int4*)(verb_ids + n * SPAN_L);
    const int4 ia = ids4[0];
    const int4 ib = ids4[1];
    int rows[SPAN_L] = {ia.x, ia.y, ia.z, ia.w, ib.x, ib.y, ib.z, ib.w};

    // Issue all gather loads first so the global_load_dwordx4 overlap.
    float4 v0[SPAN_L], v1[SPAN_L];
    #pragma unroll
    for (int l = 0; l < SPAN_L; ++l) {
        if (l < len) {
            const float4* vr = (const float4*)(V + (long)rows[l] * DW);
            v0[l] = vr[lane];
            v1[l] = tail ? vr[64 + lane] : make_float4(0.f, 0.f, 0.f, 0.f);
        } else {
            v0[l] = make_float4(0.f, 0.f, 0.f, 0.f);
            v1[l] = make_float4(0.f, 0.f, 0.f, 0.f);
        }
    }

    float s[SPAN_L];
    #pragma unroll
    for (int l = 0; l < SPAN_L; ++l) {
        float p = v0[l].x * wv0.x + v0[l].y * wv0.y + v0[l].z * wv0.z + v0[l].w * wv0.w
                + v1[l].x * wv1.x + v1[l].y * wv1.y + v1[l].z * wv1.z + v1[l].w * wv1.w;
        p = wave_reduce(p);
        s[l] = (l < len) ? (p + c) : -INFINITY;
    }

    float mx = s[0];
    #pragma unroll
    for (int l = 1; l < SPAN_L; ++l) mx = fmaxf(mx, s[l]);
    float e[SPAN_L];
    float denom = 0.f;
    #pragma unroll
    for (int l = 0; l < SPAN_L; ++l) { e[l] = __expf(s[l] - mx); denom += e[l]; }
    const float inv = 1.f / denom;

    f32x4 a0 = {0.f, 0.f, 0.f, 0.f};
    f32x4 a1 = {0.f, 0.f, 0.f, 0.f};
    #pragma unroll
    for (int l = 0; l < SPAN_L; ++l) {
        const float al = e[l] * inv;
        a0.x += al * v0[l].x; a0.y += al * v0[l].y; a0.z += al * v0[l].z; a0.w += al * v0[l].w;
        a1.x += al * v1[l].x; a1.y += al * v1[l].y; a1.z += al * v1[l].z; a1.w += al * v1[l].w;
    }

    // Nontemporal stores: out is write-once, never re-read -> don't evict V from L2/L3.
    f32x4* o4 = (f32x4*)(out + (long)n * DW);
    __builtin_nontemporal_store(a0, o4 + lane);
    if (tail) __builtin_nontemporal_store(a1, o4 + 64 + lane);
}

extern "C" void kernel_launch(void* const* d_in, const int* in_sizes, int n_in,
                              void* d_out, int out_size, void* d_ws, size_t ws_size,
                              hipStream_t stream) {
    const float* topic_emb = (const float*)d_in[0];
    const int*   verb_ids  = (const int*)  d_in[1];
    const int*   span_len  = (const int*)  d_in[2];
    const float* V         = (const float*)d_in[3];
    const float* k_w       = (const float*)d_in[4];
    const float* k_b       = (const float*)d_in[5];
    const float* q_w       = (const float*)d_in[6];
    const float* q_b       = (const float*)d_in[7];
    float* out = (float*)d_out;
    float* wc  = (float*)d_ws;   // [0..299]=w, [300]=c

    const int N = in_sizes[2];   // 16384 spans

    tva_prep<<<PREP_WBLOCKS + 1, 1024, 0, stream>>>(topic_emb, q_w, q_b, k_w, k_b, wc);
    tva_main<<<(N + 3) / 4, 256, 0, stream>>>(V, verb_ids, span_len, wc, out, N);
}

// Round 4
// 196.714 us; speedup vs baseline: 1.0564x; 1.0564x over previous
//
#include <hip/hip_runtime.h>
#include <hip/hip_bf16.h>
#include <math.h>

// Topic-verb attention over ragged spans — algebraic collapse:
//   scores[n,l] = value[n,l] . w + c,  w = (k_w^T @ query)/16, c = (k_b.query)/16
//   query = q_w @ topic_emb + q_b
// Per span: gather <=8 rows of V, dot each with w, softmax, weighted sum.
// Memory-bound on the V gather (~65 MB unique-row HBM fetch; V=120 MB).
//
// R2: nontemporal float4 stores + int4 verb_ids.            [195.3 us]
// R3: fused prep + 32-bit saddr gather                      [206.9 us REGRESSED]
// R4: fused prep + proven R2 main (decomposition)           [207.8 us REGRESSED]
//     -> regression tracks the FUSED PREP, not the gather rewrite.
// R5: full revert to the proven R0/R2 three-launch structure.
// Measured floor context: harness reset (480 MB ws fill + input restore)
// accounts for ~165 us of dur_us; controllable kernel share ~30 us.

#define SPAN_L 8
#define DW 300
#define DT 256
#define Q_OFF 320   // query[256] lives at wc[320..575]

typedef float f32x4 __attribute__((ext_vector_type(4)));

__device__ __forceinline__ float wave_reduce(float p) {
    #pragma unroll
    for (int m = 1; m < 64; m <<= 1) p += __shfl_xor(p, m, 64);
    return p;
}

// ---------- prep 1: query[r] = q_w[r,:] . topic_emb + q_b[r] ----------
__global__ __launch_bounds__(256) void tva_prep_q(
    const float* __restrict__ topic_emb,
    const float* __restrict__ q_w,
    const float* __restrict__ q_b,
    float* __restrict__ wc)
{
    const int wave = threadIdx.x >> 6;
    const int lane = threadIdx.x & 63;
    const float4 te4 = ((const float4*)topic_emb)[lane];   // 256 floats = 64 float4
    const int gw = blockIdx.x * 4 + wave;                  // 0..127
    #pragma unroll
    for (int j = 0; j < 2; ++j) {
        const int r = gw * 2 + j;                          // 0..255
        const float4 qr = ((const float4*)(q_w + r * DT))[lane];
        float p = qr.x * te4.x + qr.y * te4.y + qr.z * te4.z + qr.w * te4.w;
        p = wave_reduce(p);
        if (lane == 0) wc[Q_OFF + r] = p + q_b[r];
    }
}

// ---------- prep 2: w[d] = (sum_t k_w[t,d]*query[t])/16 ; c = (k_b.query)/16 ----
__global__ __launch_bounds__(256) void tva_prep_w(
    const float* __restrict__ k_w,
    const float* __restrict__ k_b,
    float* __restrict__ wc)
{
    __shared__ float part[4][4];
    const int b = blockIdx.x;
    const int tid = threadIdx.x;
    const int wave = tid >> 6;
    const int lane = tid & 63;

    if (b == 75) {
        if (wave == 0) {
            float p = 0.f;
            #pragma unroll
            for (int j = 0; j < 4; ++j) {
                const int t = lane + 64 * j;
                p += k_b[t] * wc[Q_OFF + t];
            }
            p = wave_reduce(p);
            if (lane == 0) wc[DW] = p * 0.0625f;
        }
        return;
    }

    const int d_off = tid & 3;           // 0..3
    const int t0 = tid >> 2;             // 0..63
    const int d = 4 * b + d_off;
    float p = 0.f;
    #pragma unroll
    for (int j = 0; j < 4; ++j) {
        const int t = t0 + 64 * j;
        p += k_w[t * DW + d] * wc[Q_OFF + t];
    }
    #pragma unroll
    for (int m = 4; m < 64; m <<= 1) p += __shfl_xor(p, m, 64);
    if (lane < 4) part[wave][lane] = p;
    __syncthreads();
    if (tid < 4)
        wc[4 * b + tid] = (part[0][tid] + part[1][tid] + part[2][tid] + part[3][tid]) * 0.0625f;
}

// ---------- main: one wave per span ----------
__global__ __launch_bounds__(256, 4) void tva_main(
    const float* __restrict__ V,          // [100000, 300]
    const int*   __restrict__ verb_ids,   // [N, 8]
    const int*   __restrict__ span_len,   // [N]
    const float* __restrict__ wc,         // [301] (+query at 320)
    float* __restrict__ out,              // [N, 300]
    int N)
{
    const int wave = threadIdx.x >> 6;
    const int lane = threadIdx.x & 63;
    const int n = blockIdx.x * 4 + wave;
    if (n >= N) return;

    const bool tail = (lane < 11);        // 300 floats = 75 float4 = 64 + 11
    const float4* w4 = (const float4*)wc;
    const float4 wv0 = w4[lane];
    const float4 wv1 = tail ? w4[64 + lane] : make_float4(0.f, 0.f, 0.f, 0.f);
    const float  c   = wc[DW];

    const int len = span_len[n];          // wave-uniform

    // ids as two int4 (wave-uniform addresses -> 2 dwordx4 instead of 8 dword)
    const int4* ids4 = (const int4*)(verb_ids + n * SPAN_L);
    const int4 ia = ids4[0];
    const int4 ib = ids4[1];
    int rows[SPAN_L] = {ia.x, ia.y, ia.z, ia.w, ib.x, ib.y, ib.z, ib.w};

    // Issue all gather loads first so the global_load_dwordx4 overlap.
    float4 v0[SPAN_L], v1[SPAN_L];
    #pragma unroll
    for (int l = 0; l < SPAN_L; ++l) {
        if (l < len) {
            const float4* vr = (const float4*)(V + (long)rows[l] * DW);
            v0[l] = vr[lane];
            v1[l] = tail ? vr[64 + lane] : make_float4(0.f, 0.f, 0.f, 0.f);
        } else {
            v0[l] = make_float4(0.f, 0.f, 0.f, 0.f);
            v1[l] = make_float4(0.f, 0.f, 0.f, 0.f);
        }
    }

    float s[SPAN_L];
    #pragma unroll
    for (int l = 0; l < SPAN_L; ++l) {
        float p = v0[l].x * wv0.x + v0[l].y * wv0.y + v0[l].z * wv0.z + v0[l].w * wv0.w
                + v1[l].x * wv1.x + v1[l].y * wv1.y + v1[l].z * wv1.z + v1[l].w * wv1.w;
        p = wave_reduce(p);
        s[l] = (l < len) ? (p + c) : -INFINITY;
    }

    float mx = s[0];
    #pragma unroll
    for (int l = 1; l < SPAN_L; ++l) mx = fmaxf(mx, s[l]);
    float e[SPAN_L];
    float denom = 0.f;
    #pragma unroll
    for (int l = 0; l < SPAN_L; ++l) { e[l] = __expf(s[l] - mx); denom += e[l]; }
    const float inv = 1.f / denom;

    f32x4 a0 = {0.f, 0.f, 0.f, 0.f};
    f32x4 a1 = {0.f, 0.f, 0.f, 0.f};
    #pragma unroll
    for (int l = 0; l < SPAN_L; ++l) {
        const float al = e[l] * inv;
        a0.x += al * v0[l].x; a0.y += al * v0[l].y; a0.z += al * v0[l].z; a0.w += al * v0[l].w;
        a1.x += al * v1[l].x; a1.y += al * v1[l].y; a1.z += al * v1[l].z; a1.w += al * v1[l].w;
    }

    // Nontemporal stores: out is write-once, never re-read -> don't evict V from L2/L3.
    f32x4* o4 = (f32x4*)(out + (long)n * DW);
    __builtin_nontemporal_store(a0, o4 + lane);
    if (tail) __builtin_nontemporal_store(a1, o4 + 64 + lane);
}

extern "C" void kernel_launch(void* const* d_in, const int* in_sizes, int n_in,
                              void* d_out, int out_size, void* d_ws, size_t ws_size,
                              hipStream_t stream) {
    const float* topic_emb = (const float*)d_in[0];
    const int*   verb_ids  = (const int*)  d_in[1];
    const int*   span_len  = (const int*)  d_in[2];
    const float* V         = (const float*)d_in[3];
    const float* k_w       = (const float*)d_in[4];
    const float* k_b       = (const float*)d_in[5];
    const float* q_w       = (const float*)d_in[6];
    const float* q_b       = (const float*)d_in[7];
    float* out = (float*)d_out;
    float* wc  = (float*)d_ws;   // [0..299]=w, [300]=c, [320..575]=query

    const int N = in_sizes[2];   // 16384 spans

    tva_prep_q<<<32, 256, 0, stream>>>(topic_emb, q_w, q_b, wc);
    tva_prep_w<<<76, 256, 0, stream>>>(k_w, k_b, wc);
    tva_main<<<(N + 3) / 4, 256, 0, stream>>>(V, verb_ids, span_len, wc, out, N);
}